// Round 8
// baseline (782.871 us; speedup 1.0000x reference)
//
#include <hip/hip_runtime.h>

// CacheFuser on MI355X (gfx950) — round 8.
// Placement rule distilled from r1-r7: the ONLY reliable way to keep a
// 64-reg accumulator in the AGPR partition is to make it an MFMA C-operand.
// r7's hsum (VALU accumulator) was arch-allocated -> arch cap 128 -> 265MB
// scratch round-trips. r1 (agg as MFMA C across 4 GEMM2s) was spill-free.
// => r8 = r1 dataflow x r7 machinery:
//  * agg accumulated in MFMA C over 4 GEMM2s (AGPR), h in AGPR;
//  * W direct from L2 (k-tile-major), barrier-free k-loops, sched_barrier;
//  * staging of next input fused into GEMM2's k-loop (rolling depth-3);
//  * fixed buffer roles: B0 = input tile, B1 = hidden tile; 12 barriers/path.
// Peak regs: GEMM1 phase ~190, GEMM2 phase ~150 (<= 256 at 2 waves/SIMD).

typedef unsigned int  u32;
typedef unsigned short u16;
typedef __attribute__((ext_vector_type(8))) short bf16x8;   // 8 x bf16
typedef __attribute__((ext_vector_type(4))) float f32x4;

#define LL   8
#define NN   4
#define HH   256
#define RPL  8192            // rows per layer = B*S
#define BM   128             // rows per block

// d_ws layout: per layer 655360 u16; per matrix: k-tile-major 8192-u16 tiles,
// tile kt holds W^T[p][kt*32..kt*32+32) as [p][32] row-major.
#define LSTRIDE 655360
#define O_AKW1 0
#define O_AKW2 65536
#define O_AVW1 131072
#define O_AVW2 196608
#define O_FKW1 262144        // K=512 -> 16 tiles (0..7 recv half, 8..15 agg half)
#define O_FKW2 393216
#define O_FVW1 458752
#define O_FVW2 589824
// total 5242880 u16 = 10485760 B in d_ws

__device__ __forceinline__ u32 f2bf(float f) {
  u32 u = __builtin_bit_cast(u32, f);
  return (u + 0x7fffu + ((u >> 16) & 1u)) >> 16;   // RNE
}

__device__ __forceinline__ float4 ldf4(const float* p) { return *(const float4*)p; }

// ---------------- prep: W[k][p] f32 -> k-tile-major bf16 W^T tiles -----------
__global__ __launch_bounds__(256) void prep_wt_k(
    const float* __restrict__ s0, const float* __restrict__ s1,
    const float* __restrict__ s2, const float* __restrict__ s3,
    const float* __restrict__ s4, const float* __restrict__ s5,
    const float* __restrict__ s6, const float* __restrict__ s7,
    u16* __restrict__ wt)
{
  __shared__ float tile[32][33];
  const int mat = blockIdx.z, l = blockIdx.y, t = blockIdx.x;
  const float* src; int off, K;
  switch (mat) {
    case 0: src = s0; off = O_AKW1; K = 256; break;
    case 1: src = s1; off = O_AKW2; K = 256; break;
    case 2: src = s2; off = O_AVW1; K = 256; break;
    case 3: src = s3; off = O_AVW2; K = 256; break;
    case 4: src = s4; off = O_FKW1; K = 512; break;
    case 5: src = s5; off = O_FKW2; K = 256; break;
    case 6: src = s6; off = O_FVW1; K = 512; break;
    default: src = s7; off = O_FVW2; K = 256; break;
  }
  const int ntk = K >> 5;
  if (t >= ntk * 8) return;                 // 8 p-tiles of 32
  const int tk = t % ntk, tp = t / ntk;
  src += (size_t)l * K * HH;
  u16* dst = wt + (size_t)l * LSTRIDE + off;
  #pragma unroll
  for (int i = 0; i < 4; ++i) {
    int idx = threadIdx.x + i * 256;
    int r = idx >> 5, c = idx & 31;        // r = k-local, c = p-local
    tile[r][c] = src[(size_t)(tk * 32 + r) * HH + tp * 32 + c];
  }
  __syncthreads();
  const int pl = threadIdx.x >> 3, kq = threadIdx.x & 7;
  const int p = tp * 32 + pl;
  ushort4 o;
  o.x = (u16)f2bf(tile[kq * 4 + 0][pl]);
  o.y = (u16)f2bf(tile[kq * 4 + 1][pl]);
  o.z = (u16)f2bf(tile[kq * 4 + 2][pl]);
  o.w = (u16)f2bf(tile[kq * 4 + 3][pl]);
  *(ushort4*)(dst + (size_t)tk * 8192 + p * 32 + kq * 4) = o;
}

// ---------------- main kernel helpers ---------------------------------------
__device__ __forceinline__ void zero44(f32x4 (&a)[4][4]) {
  f32x4 z = {0.f, 0.f, 0.f, 0.f};
  #pragma unroll
  for (int i = 0; i < 4; ++i)
    #pragma unroll
    for (int j = 0; j < 4; ++j) a[i][j] = z;
}

// D[p][q] += W^T[p][k] * Act[q][k] over K=256 (8 k-tiles), no thread barriers.
// a-frags: per-lane global loads from k-tile-major W (L2), 2-deep pipeline.
// b-frags: swizzled LDS reads.
// STG: while computing, stream a [128][256] f32 tile (src) into dst as
// swizzled bf16, one 16KB chunk per kt, depth-3 register pipeline.
// sched_barrier(0x38F) per kt: VMEM may not cross iteration boundaries.
template<bool STG>
__device__ __forceinline__ void gemm8S(
    f32x4 (&acc)[4][4], const u16* __restrict__ wtile, const u16* __restrict__ act,
    const float* __restrict__ src, u16* __restrict__ dst,
    int tid, int wp, int wq, int lr, int g)
{
  const u16* wl = wtile + (wp * 64 + lr) * 32 + g * 8;  // +fp*512, +kt*8192
  float4 slot[3][2];                                    // rolling chunks
  if (STG) {
    #pragma unroll
    for (int c = 0; c < 3; ++c) {
      slot[c][0] = ldf4(src + (size_t)(c * 1024 + tid) * 4);
      slot[c][1] = ldf4(src + (size_t)(c * 1024 + 512 + tid) * 4);
    }
  }
  bf16x8 a[2][4];
  #pragma unroll
  for (int fp = 0; fp < 4; ++fp) a[0][fp] = *(const bf16x8*)(wl + fp * 512);
  #pragma unroll
  for (int kt = 0; kt < 8; ++kt) {
    const int cur = kt & 1;
    if (kt < 7) {
      #pragma unroll
      for (int fp = 0; fp < 4; ++fp)
        a[cur ^ 1][fp] = *(const bf16x8*)(wl + (kt + 1) * 8192 + fp * 512);
    }
    bf16x8 b[4];
    #pragma unroll
    for (int fq = 0; fq < 4; ++fq) {
      int q = wq * 64 + fq * 16 + lr;
      int k = (kt * 32 + g * 8) ^ ((q & 7) << 3);
      b[fq] = *(const bf16x8*)(act + q * HH + k);
    }
    if (STG) {
      const int s = kt % 3;                 // compile-time after unroll
      #pragma unroll
      for (int h = 0; h < 2; ++h) {
        int idx = kt * 1024 + h * 512 + tid;
        int q = idx >> 6, c = (idx & 63) * 4;
        const float4& v = slot[s][h];
        ushort4 o;
        o.x = (u16)f2bf(v.x); o.y = (u16)f2bf(v.y);
        o.z = (u16)f2bf(v.z); o.w = (u16)f2bf(v.w);
        *(ushort4*)(dst + q * HH + (c ^ ((q & 7) << 3))) = o;
      }
      if (kt + 3 < 8) {
        slot[s][0] = ldf4(src + (size_t)((kt + 3) * 1024 + tid) * 4);
        slot[s][1] = ldf4(src + (size_t)((kt + 3) * 1024 + 512 + tid) * 4);
      }
    }
    #pragma unroll
    for (int fp = 0; fp < 4; ++fp)
      #pragma unroll
      for (int fq = 0; fq < 4; ++fq)
        acc[fp][fq] = __builtin_amdgcn_mfma_f32_16x16x32_bf16(a[cur][fp], b[fq], acc[fp][fq], 0, 0, 0);
    __builtin_amdgcn_sched_barrier(0x38F);
  }
}

// One-shot staging (prologue): [128][256] f32 -> swizzled bf16 LDS.
__device__ __forceinline__ void stageDirect(u16* dst, const float* __restrict__ src, int tid) {
  #pragma unroll
  for (int i = 0; i < 16; ++i) {
    int idx = i * 512 + tid;
    float4 v = ldf4(src + (size_t)idx * 4);
    int q = idx >> 6, c = (idx & 63) * 4;
    ushort4 o;
    o.x = (u16)f2bf(v.x); o.y = (u16)f2bf(v.y);
    o.z = (u16)f2bf(v.z); o.w = (u16)f2bf(v.w);
    *(ushort4*)(dst + q * HH + (c ^ ((q & 7) << 3))) = o;
  }
}

// acc -> swizzled bf16 LDS: v = [relu?](acc + bscale*bias) * post
__device__ __forceinline__ void epiLds(
    u16* buf, f32x4 (&acc)[4][4], const float* __restrict__ bias,
    float bscale, float post, bool doRelu, int wp, int wq, int lr, int g)
{
  #pragma unroll
  for (int fp = 0; fp < 4; ++fp) {
    int p0 = wp * 64 + fp * 16 + g * 4;
    float4 bv = *(const float4*)(bias + p0);
    #pragma unroll
    for (int fq = 0; fq < 4; ++fq) {
      int q = wq * 64 + fq * 16 + lr;
      float v0 = acc[fp][fq][0] + bscale * bv.x;
      float v1 = acc[fp][fq][1] + bscale * bv.y;
      float v2 = acc[fp][fq][2] + bscale * bv.z;
      float v3 = acc[fp][fq][3] + bscale * bv.w;
      if (doRelu) {
        v0 = fmaxf(v0, 0.f); v1 = fmaxf(v1, 0.f);
        v2 = fmaxf(v2, 0.f); v3 = fmaxf(v3, 0.f);
      }
      ushort4 o;
      o.x = (u16)f2bf(v0 * post); o.y = (u16)f2bf(v1 * post);
      o.z = (u16)f2bf(v2 * post); o.w = (u16)f2bf(v3 * post);
      *(ushort4*)(buf + q * HH + (p0 ^ ((q & 7) << 3))) = o;
    }
  }
}

// out = recv + gate*(acc + bias)
__device__ __forceinline__ void epiOut(
    f32x4 (&acc)[4][4], const float* __restrict__ bias,
    const float* __restrict__ recv, float* __restrict__ outp,
    float gate, int wp, int wq, int lr, int g)
{
  #pragma unroll
  for (int fp = 0; fp < 4; ++fp) {
    int p0 = wp * 64 + fp * 16 + g * 4;
    float4 bv = *(const float4*)(bias + p0);
    #pragma unroll
    for (int fq = 0; fq < 4; ++fq) {
      int q = wq * 64 + fq * 16 + lr;
      float4 rv = *(const float4*)(recv + (size_t)q * HH + p0);
      float4 ov;
      ov.x = rv.x + gate * (acc[fp][fq][0] + bv.x);
      ov.y = rv.y + gate * (acc[fp][fq][1] + bv.y);
      ov.z = rv.z + gate * (acc[fp][fq][2] + bv.z);
      ov.w = rv.w + gate * (acc[fp][fq][3] + bv.w);
      *(float4*)(outp + (size_t)q * HH + p0) = ov;
    }
  }
}

__global__ __launch_bounds__(512) void CacheFuser_73873437491748_kernel(
    const float* __restrict__ recv_k, const float* __restrict__ recv_v,
    const float* __restrict__ shar_k, const float* __restrict__ shar_v,
    const float* __restrict__ ew, const float* __restrict__ alpha,
    const float* __restrict__ ak_b1, const float* __restrict__ ak_b2,
    const float* __restrict__ av_b1, const float* __restrict__ av_b2,
    const float* __restrict__ fk_b1, const float* __restrict__ fk_b2,
    const float* __restrict__ fv_b1, const float* __restrict__ fv_b2,
    const u16* __restrict__ wt, float* __restrict__ out)
{
  __shared__ u16 B0[BM * HH];   // 64 KB, swizzled. INPUT tile (sharer_n / recv).
  __shared__ u16 B1[BM * HH];   // 64 KB. HIDDEN tile (relu / agg / fuse-hidden).

  const int bid = blockIdx.x;
  const int l = bid & 7, t = bid >> 3;          // layer <-> XCD affinity
  const int tid = threadIdx.x;
  const int w = tid >> 6, lane = tid & 63, lr = lane & 15, g = lane >> 4;
  const int wp = w & 3, wq = w >> 2;

  const size_t row0 = (size_t)t * BM;
  const u16* lw = wt + (size_t)l * LSTRIDE;
  const float gate = 1.f / (1.f + __expf(-2.f * alpha[l]));
  const float* ewl = ew + l * NN;

  stageDirect(B0, shar_k + ((size_t)l * NN * RPL + row0) * HH, tid);  // K sharer0

  #pragma unroll 1
  for (int path = 0; path < 2; ++path) {
    const float* recvB = (path ? recv_v : recv_k) + ((size_t)l * RPL + row0) * HH;
    const float* sharB = (path ? shar_v : shar_k) + ((size_t)l * NN * RPL + row0) * HH;
    const u16* W1  = lw + (path ? O_AVW1 : O_AKW1);
    const u16* W2  = lw + (path ? O_AVW2 : O_AKW2);
    const u16* FW1 = lw + (path ? O_FVW1 : O_FKW1);
    const u16* FW2 = lw + (path ? O_FVW2 : O_FKW2);
    const float* b1  = (path ? av_b1 : ak_b1) + l * HH;
    const float* b2  = (path ? av_b2 : ak_b2) + l * HH;
    const float* fb1 = (path ? fv_b1 : fk_b1) + l * HH;
    const float* fb2 = (path ? fv_b2 : fk_b2) + l * HH;
    float* outp = out + ((size_t)(path * LL + l) * RPL + row0) * HH;

    f32x4 agg[4][4]; zero44(agg);      // AGPR: MFMA C across all 4 GEMM2s
    float sS = 0.f;

    #pragma unroll 1
    for (int n = 0; n < NN; ++n) {
      float sn = ewl[n] * 0.25f; sS += sn;
      __syncthreads();                               // B0 = input n ready;
                                                     // prev GEMM2's B1 reads done
      f32x4 h[4][4]; zero44(h);
      gemm8S<false>(h, W1, B0, nullptr, nullptr, tid, wp, wq, lr, g);
      epiLds(B1, h, b1, 1.f, sn, true, wp, wq, lr, g);   // B1 = sn*relu(h+b1)
      __syncthreads();                               // B1 ready; B0 reads done
      const float* nsrc = (n < 3) ? sharB + (size_t)(n + 1) * RPL * HH : recvB;
      // agg += W2*B1, while streaming next input -> B0
      gemm8S<true>(agg, W2, B1, nsrc, B0, tid, wp, wq, lr, g);
    }
    __syncthreads();                                 // B0 = recv ready; B1 free
    epiLds(B1, agg, b2, sS, 1.f, false, wp, wq, lr, g);   // B1 = agg + sS*b2
    __syncthreads();
    f32x4 h2[4][4]; zero44(h2);
    gemm8S<false>(h2, FW1, B0, nullptr, nullptr, tid, wp, wq, lr, g);            // recv half
    gemm8S<false>(h2, FW1 + 8 * 8192, B1, nullptr, nullptr, tid, wp, wq, lr, g); // agg half
    __syncthreads();                                 // B0/B1 reads done
    epiLds(B1, h2, fb1, 1.f, 1.f, true, wp, wq, lr, g);   // B1 = fuse hidden
    __syncthreads();
    f32x4 dd[4][4]; zero44(dd);
    if (path == 0) {
      // delta GEMM while streaming V-path sharer0 -> B0
      gemm8S<true>(dd, FW2, B1, shar_v + ((size_t)l * NN * RPL + row0) * HH, B0,
                   tid, wp, wq, lr, g);
    } else {
      gemm8S<false>(dd, FW2, B1, nullptr, nullptr, tid, wp, wq, lr, g);
    }
    epiOut(dd, fb2, recvB, outp, gate, wp, wq, lr, g);
  }
}

extern "C" void kernel_launch(void* const* d_in, const int* in_sizes, int n_in,
                              void* d_out, int out_size, void* d_ws, size_t ws_size,
                              hipStream_t stream)
{
  const float* recv_k = (const float*)d_in[0];
  const float* recv_v = (const float*)d_in[1];
  const float* shar_k = (const float*)d_in[2];
  const float* shar_v = (const float*)d_in[3];
  const float* ew     = (const float*)d_in[4];
  const float* alpha  = (const float*)d_in[5];
  const float* ak_w1 = (const float*)d_in[6];  const float* ak_b1 = (const float*)d_in[7];
  const float* ak_w2 = (const float*)d_in[8];  const float* ak_b2 = (const float*)d_in[9];
  const float* av_w1 = (const float*)d_in[10]; const float* av_b1 = (const float*)d_in[11];
  const float* av_w2 = (const float*)d_in[12]; const float* av_b2 = (const float*)d_in[13];
  const float* fk_w1 = (const float*)d_in[14]; const float* fk_b1 = (const float*)d_in[15];
  const float* fk_w2 = (const float*)d_in[16]; const float* fk_b2 = (const float*)d_in[17];
  const float* fv_w1 = (const float*)d_in[18]; const float* fv_b1 = (const float*)d_in[19];
  const float* fv_w2 = (const float*)d_in[20]; const float* fv_b2 = (const float*)d_in[21];
  u16* wtw = (u16*)d_ws;          // 10485760 B
  float* outp = (float*)d_out;

  prep_wt_k<<<dim3(128, 8, 8), dim3(256), 0, stream>>>(
      ak_w1, ak_w2, av_w1, av_w2, fk_w1, fk_w2, fv_w1, fv_w2, wtw);

  CacheFuser_73873437491748_kernel<<<dim3(512), dim3(512), 0, stream>>>(
      recv_k, recv_v, shar_k, shar_v, ew, alpha,
      ak_b1, ak_b2, av_b1, av_b2, fk_b1, fk_b2, fv_b1, fv_b2, wtw, outp);
}

// Round 9
// 405.731 us; speedup vs baseline: 1.9295x; 1.9295x over previous
//
#include <hip/hip_runtime.h>

// CacheFuser on MI355X (gfx950) — round 9.
// Lesson of r1-r8: any design holding TWO 64-reg accumulators (or a 64-reg
// VALU array) spills; the allocator gives us ~128 arch regs. So make the
// register problem trivial:
//  * ONE accumulator alive at a time: acc[4][2]=32 regs (BM=64, wave 64p x 32q).
//  * r7 linearity algebra (ONE GEMM2/path) with the hidden-sum accumulated in
//    LDS bf16 by owner-exclusive RMW (no races, no barriers, no registers).
//    Extra rounding error ~0.002 vs 0.031 margin.
//  * X ping-pong 2x32KB + HS 32KB = 96KB LDS; staging fused into k-loops with
//    a 4-deep rolling pipeline (16 regs); W direct from L2 (k-tile-major).
// Total demand ~120 regs: fits even a 128-total budget.

typedef unsigned int  u32;
typedef unsigned short u16;
typedef __attribute__((ext_vector_type(8))) short bf16x8;   // 8 x bf16
typedef __attribute__((ext_vector_type(4))) float f32x4;

#define LL   8
#define NN   4
#define HH   256
#define RPL  8192            // rows per layer = B*S
#define BM   64              // rows per block

// d_ws layout: per layer 655360 u16; per matrix: k-tile-major 8192-u16 tiles,
// tile kt holds W^T[p][kt*32..kt*32+32) as [p][32] row-major.
#define LSTRIDE 655360
#define O_AKW1 0
#define O_AKW2 65536
#define O_AVW1 131072
#define O_AVW2 196608
#define O_FKW1 262144        // K=512 -> 16 tiles (0..7 recv half, 8..15 agg half)
#define O_FKW2 393216
#define O_FVW1 458752
#define O_FVW2 589824
// total 5242880 u16 = 10485760 B in d_ws

__device__ __forceinline__ u32 f2bf(float f) {
  u32 u = __builtin_bit_cast(u32, f);
  return (u + 0x7fffu + ((u >> 16) & 1u)) >> 16;   // RNE
}
__device__ __forceinline__ float bf2f(u16 b) {
  u32 u = ((u32)b) << 16;
  return __builtin_bit_cast(float, u);
}
__device__ __forceinline__ float4 ldf4(const float* p) { return *(const float4*)p; }

// ---------------- prep: W[k][p] f32 -> k-tile-major bf16 W^T tiles -----------
__global__ __launch_bounds__(256) void prep_wt_k(
    const float* __restrict__ s0, const float* __restrict__ s1,
    const float* __restrict__ s2, const float* __restrict__ s3,
    const float* __restrict__ s4, const float* __restrict__ s5,
    const float* __restrict__ s6, const float* __restrict__ s7,
    u16* __restrict__ wt)
{
  __shared__ float tile[32][33];
  const int mat = blockIdx.z, l = blockIdx.y, t = blockIdx.x;
  const float* src; int off, K;
  switch (mat) {
    case 0: src = s0; off = O_AKW1; K = 256; break;
    case 1: src = s1; off = O_AKW2; K = 256; break;
    case 2: src = s2; off = O_AVW1; K = 256; break;
    case 3: src = s3; off = O_AVW2; K = 256; break;
    case 4: src = s4; off = O_FKW1; K = 512; break;
    case 5: src = s5; off = O_FKW2; K = 256; break;
    case 6: src = s6; off = O_FVW1; K = 512; break;
    default: src = s7; off = O_FVW2; K = 256; break;
  }
  const int ntk = K >> 5;
  if (t >= ntk * 8) return;                 // 8 p-tiles of 32
  const int tk = t % ntk, tp = t / ntk;
  src += (size_t)l * K * HH;
  u16* dst = wt + (size_t)l * LSTRIDE + off;
  #pragma unroll
  for (int i = 0; i < 4; ++i) {
    int idx = threadIdx.x + i * 256;
    int r = idx >> 5, c = idx & 31;        // r = k-local, c = p-local
    tile[r][c] = src[(size_t)(tk * 32 + r) * HH + tp * 32 + c];
  }
  __syncthreads();
  const int pl = threadIdx.x >> 3, kq = threadIdx.x & 7;
  const int p = tp * 32 + pl;
  ushort4 o;
  o.x = (u16)f2bf(tile[kq * 4 + 0][pl]);
  o.y = (u16)f2bf(tile[kq * 4 + 1][pl]);
  o.z = (u16)f2bf(tile[kq * 4 + 2][pl]);
  o.w = (u16)f2bf(tile[kq * 4 + 3][pl]);
  *(ushort4*)(dst + (size_t)tk * 8192 + p * 32 + kq * 4) = o;
}

// ---------------- main kernel helpers ---------------------------------------
__device__ __forceinline__ void zero42(f32x4 (&a)[4][2]) {
  f32x4 z = {0.f, 0.f, 0.f, 0.f};
  #pragma unroll
  for (int i = 0; i < 4; ++i) { a[i][0] = z; a[i][1] = z; }
}

// D[p][q] += W^T[p][k] * Act[q][k] over K=256 (8 k-tiles), no thread barriers.
// a-frags: per-lane global loads from k-tile-major W (L2), 2-deep pipeline.
// b-frags: swizzled LDS reads from a [64][256] bf16 buffer.
// STG: while computing, stream a [64][256] f32 tile (src) into dst as
// swizzled bf16, one 4KB chunk per kt, 4-deep rolling register pipeline.
template<bool STG>
__device__ __forceinline__ void gemm8S(
    f32x4 (&acc)[4][2], const u16* __restrict__ wtile, const u16* __restrict__ act,
    const float* __restrict__ src, u16* __restrict__ dst,
    int tid, int wp, int wq, int lr, int g)
{
  const u16* wl = wtile + (wp * 64 + lr) * 32 + g * 8;  // +fp*512, +kt*8192
  float4 slot[4];                                       // rolling chunks
  if (STG) {
    #pragma unroll
    for (int c = 0; c < 4; ++c)
      slot[c] = ldf4(src + (size_t)(c * 512 + tid) * 4);
  }
  bf16x8 a[2][4];
  #pragma unroll
  for (int fp = 0; fp < 4; ++fp) a[0][fp] = *(const bf16x8*)(wl + fp * 512);
  #pragma unroll
  for (int kt = 0; kt < 8; ++kt) {
    const int cur = kt & 1;
    if (kt < 7) {
      #pragma unroll
      for (int fp = 0; fp < 4; ++fp)
        a[cur ^ 1][fp] = *(const bf16x8*)(wl + (kt + 1) * 8192 + fp * 512);
    }
    bf16x8 b[2];
    #pragma unroll
    for (int fq = 0; fq < 2; ++fq) {
      int q = wq * 32 + fq * 16 + lr;
      int k = (kt * 32 + g * 8) ^ ((q & 7) << 3);
      b[fq] = *(const bf16x8*)(act + q * HH + k);
    }
    if (STG) {
      // write chunk kt (8 rows), then load chunk kt+4
      const int s = kt & 3;
      int q = kt * 8 + (tid >> 6), c = (tid & 63) * 4;
      const float4& v = slot[s];
      ushort4 o;
      o.x = (u16)f2bf(v.x); o.y = (u16)f2bf(v.y);
      o.z = (u16)f2bf(v.z); o.w = (u16)f2bf(v.w);
      *(ushort4*)(dst + q * HH + (c ^ ((q & 7) << 3))) = o;
      if (kt + 4 < 8)
        slot[s] = ldf4(src + (size_t)((kt + 4) * 512 + tid) * 4);
    }
    #pragma unroll
    for (int fp = 0; fp < 4; ++fp)
      #pragma unroll
      for (int fq = 0; fq < 2; ++fq)
        acc[fp][fq] = __builtin_amdgcn_mfma_f32_16x16x32_bf16(a[cur][fp], b[fq], acc[fp][fq], 0, 0, 0);
    __builtin_amdgcn_sched_barrier(0x38F);
  }
}

// One-shot staging (prologue): [64][256] f32 -> swizzled bf16 LDS.
__device__ __forceinline__ void stageDirect(u16* dst, const float* __restrict__ src, int tid) {
  #pragma unroll
  for (int i = 0; i < 8; ++i) {
    int idx = i * 512 + tid;
    float4 v = ldf4(src + (size_t)idx * 4);
    int q = i * 8 + (tid >> 6), c = (tid & 63) * 4;
    ushort4 o;
    o.x = (u16)f2bf(v.x); o.y = (u16)f2bf(v.y);
    o.z = (u16)f2bf(v.z); o.w = (u16)f2bf(v.w);
    *(ushort4*)(dst + q * HH + (c ^ ((q & 7) << 3))) = o;
  }
}

// HS (owner-exclusive RMW): HS[p][q] (+)= sn * relu(acc + b1)   [bf16 in LDS]
template<bool INIT>
__device__ __forceinline__ void hsUpd(
    u16* HS, f32x4 (&acc)[4][2], const float* __restrict__ b1,
    float sn, int wp, int wq, int lr, int g)
{
  #pragma unroll
  for (int fp = 0; fp < 4; ++fp) {
    int p0 = wp * 64 + fp * 16 + g * 4;
    float4 bv = *(const float4*)(b1 + p0);
    #pragma unroll
    for (int fq = 0; fq < 2; ++fq) {
      int q = wq * 32 + fq * 16 + lr;
      u16* addr = HS + q * HH + (p0 ^ ((q & 7) << 3));
      float v0 = sn * fmaxf(acc[fp][fq][0] + bv.x, 0.f);
      float v1 = sn * fmaxf(acc[fp][fq][1] + bv.y, 0.f);
      float v2 = sn * fmaxf(acc[fp][fq][2] + bv.z, 0.f);
      float v3 = sn * fmaxf(acc[fp][fq][3] + bv.w, 0.f);
      if (!INIT) {
        ushort4 old = *(ushort4*)addr;
        v0 += bf2f(old.x); v1 += bf2f(old.y);
        v2 += bf2f(old.z); v3 += bf2f(old.w);
      }
      ushort4 o;
      o.x = (u16)f2bf(v0); o.y = (u16)f2bf(v1);
      o.z = (u16)f2bf(v2); o.w = (u16)f2bf(v3);
      *(ushort4*)addr = o;
    }
  }
}

// acc -> swizzled bf16 LDS: v = [relu?](acc + bscale*bias)
__device__ __forceinline__ void epiLds(
    u16* buf, f32x4 (&acc)[4][2], const float* __restrict__ bias,
    float bscale, bool doRelu, int wp, int wq, int lr, int g)
{
  #pragma unroll
  for (int fp = 0; fp < 4; ++fp) {
    int p0 = wp * 64 + fp * 16 + g * 4;
    float4 bv = *(const float4*)(bias + p0);
    #pragma unroll
    for (int fq = 0; fq < 2; ++fq) {
      int q = wq * 32 + fq * 16 + lr;
      float v0 = acc[fp][fq][0] + bscale * bv.x;
      float v1 = acc[fp][fq][1] + bscale * bv.y;
      float v2 = acc[fp][fq][2] + bscale * bv.z;
      float v3 = acc[fp][fq][3] + bscale * bv.w;
      if (doRelu) {
        v0 = fmaxf(v0, 0.f); v1 = fmaxf(v1, 0.f);
        v2 = fmaxf(v2, 0.f); v3 = fmaxf(v3, 0.f);
      }
      ushort4 o;
      o.x = (u16)f2bf(v0); o.y = (u16)f2bf(v1);
      o.z = (u16)f2bf(v2); o.w = (u16)f2bf(v3);
      *(ushort4*)(buf + q * HH + (p0 ^ ((q & 7) << 3))) = o;
    }
  }
}

// out = recv + gate*(acc + bias)
__device__ __forceinline__ void epiOut(
    f32x4 (&acc)[4][2], const float* __restrict__ bias,
    const float* __restrict__ recv, float* __restrict__ outp,
    float gate, int wp, int wq, int lr, int g)
{
  #pragma unroll
  for (int fp = 0; fp < 4; ++fp) {
    int p0 = wp * 64 + fp * 16 + g * 4;
    float4 bv = *(const float4*)(bias + p0);
    #pragma unroll
    for (int fq = 0; fq < 2; ++fq) {
      int q = wq * 32 + fq * 16 + lr;
      float4 rv = *(const float4*)(recv + (size_t)q * HH + p0);
      float4 ov;
      ov.x = rv.x + gate * (acc[fp][fq][0] + bv.x);
      ov.y = rv.y + gate * (acc[fp][fq][1] + bv.y);
      ov.z = rv.z + gate * (acc[fp][fq][2] + bv.z);
      ov.w = rv.w + gate * (acc[fp][fq][3] + bv.w);
      *(float4*)(outp + (size_t)q * HH + p0) = ov;
    }
  }
}

__global__ __launch_bounds__(512) void CacheFuser_73873437491748_kernel(
    const float* __restrict__ recv_k, const float* __restrict__ recv_v,
    const float* __restrict__ shar_k, const float* __restrict__ shar_v,
    const float* __restrict__ ew, const float* __restrict__ alpha,
    const float* __restrict__ ak_b1, const float* __restrict__ ak_b2,
    const float* __restrict__ av_b1, const float* __restrict__ av_b2,
    const float* __restrict__ fk_b1, const float* __restrict__ fk_b2,
    const float* __restrict__ fv_b1, const float* __restrict__ fv_b2,
    const u16* __restrict__ wt, float* __restrict__ out)
{
  __shared__ u16 XA[BM * HH];   // 32 KB input ping
  __shared__ u16 XB[BM * HH];   // 32 KB input pong
  __shared__ u16 HS[BM * HH];   // 32 KB hidden-sum / agg / fuse-hidden
  // total 96 KB

  const int bid = blockIdx.x;
  const int l = bid & 7, t = bid >> 3;          // layer <-> XCD affinity
  const int tid = threadIdx.x;
  const int w = tid >> 6, lane = tid & 63, lr = lane & 15, g = lane >> 4;
  const int wp = w & 3, wq = w >> 2;            // 4 p-tiles x 2 q-tiles

  const size_t row0 = (size_t)t * BM;
  const u16* lw = wt + (size_t)l * LSTRIDE;
  const float gate = 1.f / (1.f + __expf(-2.f * alpha[l]));
  const float* ewl = ew + l * NN;

  stageDirect(XA, shar_k + ((size_t)l * NN * RPL + row0) * HH, tid);  // K sharer0

  #pragma unroll 1
  for (int path = 0; path < 2; ++path) {
    const float* recvB = (path ? recv_v : recv_k) + ((size_t)l * RPL + row0) * HH;
    const float* sharB = (path ? shar_v : shar_k) + ((size_t)l * NN * RPL + row0) * HH;
    const u16* W1  = lw + (path ? O_AVW1 : O_AKW1);
    const u16* W2  = lw + (path ? O_AVW2 : O_AKW2);
    const u16* FW1 = lw + (path ? O_FVW1 : O_FKW1);
    const u16* FW2 = lw + (path ? O_FVW2 : O_FKW2);
    const float* b1  = (path ? av_b1 : ak_b1) + l * HH;
    const float* b2  = (path ? av_b2 : ak_b2) + l * HH;
    const float* fb1 = (path ? fv_b1 : fk_b1) + l * HH;
    const float* fb2 = (path ? fv_b2 : fk_b2) + l * HH;
    float* outp = out + ((size_t)(path * LL + l) * RPL + row0) * HH;

    int cur = path;                 // path0 input starts in XA, path1 in XB
    float sS = 0.f;

    #pragma unroll 1
    for (int n = 0; n < NN; ++n) {
      float sn = ewl[n] * 0.25f; sS += sn;
      __syncthreads();                         // buf[cur] = input n ready
      u16* XC = cur ? XB : XA;
      u16* XO = cur ? XA : XB;
      const float* nsrc = (n < 3) ? sharB + (size_t)(n + 1) * RPL * HH : recvB;
      f32x4 h[4][2]; zero42(h);
      gemm8S<true>(h, W1, XC, nsrc, XO, tid, wp, wq, lr, g);
      if (n == 0) hsUpd<true >(HS, h, b1, sn, wp, wq, lr, g);
      else        hsUpd<false>(HS, h, b1, sn, wp, wq, lr, g);
      cur ^= 1;
    }
    __syncthreads();                           // HS complete; recv staged
    u16* XR = cur ? XB : XA;                   // recv buffer
    u16* XF = cur ? XA : XB;                   // free buffer (next-path target)
    f32x4 agg[4][2]; zero42(agg);
    gemm8S<false>(agg, W2, HS, nullptr, nullptr, tid, wp, wq, lr, g);
    __syncthreads();                           // all reads of HS done
    epiLds(HS, agg, b2, sS, false, wp, wq, lr, g);   // HS = agg + sS*b2
    __syncthreads();
    f32x4 h2[4][2]; zero42(h2);
    gemm8S<false>(h2, FW1, XR, nullptr, nullptr, tid, wp, wq, lr, g);            // recv half
    gemm8S<false>(h2, FW1 + 8 * 8192, HS, nullptr, nullptr, tid, wp, wq, lr, g); // agg half
    __syncthreads();                           // all reads of HS done
    epiLds(HS, h2, fb1, 1.f, true, wp, wq, lr, g);   // HS = fuse hidden
    __syncthreads();
    f32x4 dd[4][2]; zero42(dd);
    if (path == 0) {
      // delta GEMM while streaming V-path sharer0 -> XF
      gemm8S<true>(dd, FW2, HS, shar_v + ((size_t)l * NN * RPL + row0) * HH, XF,
                   tid, wp, wq, lr, g);
    } else {
      gemm8S<false>(dd, FW2, HS, nullptr, nullptr, tid, wp, wq, lr, g);
    }
    epiOut(dd, fb2, recvB, outp, gate, wp, wq, lr, g);
  }
}

extern "C" void kernel_launch(void* const* d_in, const int* in_sizes, int n_in,
                              void* d_out, int out_size, void* d_ws, size_t ws_size,
                              hipStream_t stream)
{
  const float* recv_k = (const float*)d_in[0];
  const float* recv_v = (const float*)d_in[1];
  const float* shar_k = (const float*)d_in[2];
  const float* shar_v = (const float*)d_in[3];
  const float* ew     = (const float*)d_in[4];
  const float* alpha  = (const float*)d_in[5];
  const float* ak_w1 = (const float*)d_in[6];  const float* ak_b1 = (const float*)d_in[7];
  const float* ak_w2 = (const float*)d_in[8];  const float* ak_b2 = (const float*)d_in[9];
  const float* av_w1 = (const float*)d_in[10]; const float* av_b1 = (const float*)d_in[11];
  const float* av_w2 = (const float*)d_in[12]; const float* av_b2 = (const float*)d_in[13];
  const float* fk_w1 = (const float*)d_in[14]; const float* fk_b1 = (const float*)d_in[15];
  const float* fk_w2 = (const float*)d_in[16]; const float* fk_b2 = (const float*)d_in[17];
  const float* fv_w1 = (const float*)d_in[18]; const float* fv_b1 = (const float*)d_in[19];
  const float* fv_w2 = (const float*)d_in[20]; const float* fv_b2 = (const float*)d_in[21];
  u16* wtw = (u16*)d_ws;          // 10485760 B
  float* outp = (float*)d_out;

  prep_wt_k<<<dim3(128, 8, 8), dim3(256), 0, stream>>>(
      ak_w1, ak_w2, av_w1, av_w2, fk_w1, fk_w2, fv_w1, fv_w2, wtw);

  CacheFuser_73873437491748_kernel<<<dim3(1024), dim3(512), 0, stream>>>(
      recv_k, recv_v, shar_k, shar_v, ew, alpha,
      ak_b1, ak_b2, av_b1, av_b2, fk_b1, fk_b2, fv_b1, fv_b2, wtw, outp);
}

// Round 11
// 375.030 us; speedup vs baseline: 2.0875x; 1.0819x over previous
//
#include <hip/hip_runtime.h>

// CacheFuser on MI355X (gfx950) — round 10b (compile fix of r10).
// r10's `u16* X[2] = {XA, XB}` created an addrspacecast static initializer
// (LDS -> generic) that hipcc rejects on gfx950. Replaced with ternary
// selection (r9 pattern). Design unchanged:
//  * BM=32, LDS = 16+16+32 = 64KB -> 2 blocks/CU (4 waves/SIMD, independent).
//  * 8 waves = 8 DISTINCT 32-row W slices -> W L2 traffic halved;
//    wave tile 32p x 32q, acc[2][2] = 16 regs.
//  * hidden-sum in f32 LDS (HF, owner-exclusive RMW); convert pass -> bf16 in
//    dead X buffer for GEMM2; HF reused as two bf16 scratch tiles.
//  * __launch_bounds__(512,4): 128-reg budget, demand ~95.
//  * staging fused per-2-kt; a[0] loads ordered before slot loads.

typedef unsigned int  u32;
typedef unsigned short u16;
typedef __attribute__((ext_vector_type(8))) short bf16x8;   // 8 x bf16
typedef __attribute__((ext_vector_type(4))) float f32x4;

#define LL   8
#define NN   4
#define HH   256
#define RPL  8192            // rows per layer = B*S
#define BM   32              // rows per block

// d_ws layout: per layer 655360 u16; per matrix: k-tile-major 8192-u16 tiles,
// tile kt holds W^T[p][kt*32..kt*32+32) as [p][32] row-major.
#define LSTRIDE 655360
#define O_AKW1 0
#define O_AKW2 65536
#define O_AVW1 131072
#define O_AVW2 196608
#define O_FKW1 262144        // K=512 -> 16 tiles (0..7 recv half, 8..15 agg half)
#define O_FKW2 393216
#define O_FVW1 458752
#define O_FVW2 589824
// total 5242880 u16 = 10485760 B in d_ws

__device__ __forceinline__ u32 f2bf(float f) {
  u32 u = __builtin_bit_cast(u32, f);
  return (u + 0x7fffu + ((u >> 16) & 1u)) >> 16;   // RNE
}
__device__ __forceinline__ float4 ldf4(const float* p) { return *(const float4*)p; }

// ---------------- prep: W[k][p] f32 -> k-tile-major bf16 W^T tiles -----------
__global__ __launch_bounds__(256) void prep_wt_k(
    const float* __restrict__ s0, const float* __restrict__ s1,
    const float* __restrict__ s2, const float* __restrict__ s3,
    const float* __restrict__ s4, const float* __restrict__ s5,
    const float* __restrict__ s6, const float* __restrict__ s7,
    u16* __restrict__ wt)
{
  __shared__ float tile[32][33];
  const int mat = blockIdx.z, l = blockIdx.y, t = blockIdx.x;
  const float* src; int off, K;
  switch (mat) {
    case 0: src = s0; off = O_AKW1; K = 256; break;
    case 1: src = s1; off = O_AKW2; K = 256; break;
    case 2: src = s2; off = O_AVW1; K = 256; break;
    case 3: src = s3; off = O_AVW2; K = 256; break;
    case 4: src = s4; off = O_FKW1; K = 512; break;
    case 5: src = s5; off = O_FKW2; K = 256; break;
    case 6: src = s6; off = O_FVW1; K = 512; break;
    default: src = s7; off = O_FVW2; K = 256; break;
  }
  const int ntk = K >> 5;
  if (t >= ntk * 8) return;                 // 8 p-tiles of 32
  const int tk = t % ntk, tp = t / ntk;
  src += (size_t)l * K * HH;
  u16* dst = wt + (size_t)l * LSTRIDE + off;
  #pragma unroll
  for (int i = 0; i < 4; ++i) {
    int idx = threadIdx.x + i * 256;
    int r = idx >> 5, c = idx & 31;        // r = k-local, c = p-local
    tile[r][c] = src[(size_t)(tk * 32 + r) * HH + tp * 32 + c];
  }
  __syncthreads();
  const int pl = threadIdx.x >> 3, kq = threadIdx.x & 7;
  const int p = tp * 32 + pl;
  ushort4 o;
  o.x = (u16)f2bf(tile[kq * 4 + 0][pl]);
  o.y = (u16)f2bf(tile[kq * 4 + 1][pl]);
  o.z = (u16)f2bf(tile[kq * 4 + 2][pl]);
  o.w = (u16)f2bf(tile[kq * 4 + 3][pl]);
  *(ushort4*)(dst + (size_t)tk * 8192 + p * 32 + kq * 4) = o;
}

// ---------------- main kernel helpers ---------------------------------------
__device__ __forceinline__ void zero22(f32x4 (&a)[2][2]) {
  f32x4 z = {0.f, 0.f, 0.f, 0.f};
  a[0][0] = z; a[0][1] = z; a[1][0] = z; a[1][1] = z;
}

// D[p][q] += W^T[p][k] * Act[q][k] over K=256 (8 k-tiles), no thread barriers.
// Wave w owns p in [w*32, w*32+32): a-frags distinct across waves (no dup).
// b-frags: swizzled LDS reads from a [32][256] bf16 buffer.
// STG: stream a [32][256] f32 tile (src) into dst as swizzled bf16; 4 slots
// loaded at entry, one 8-row chunk written every odd kt.
template<bool STG>
__device__ __forceinline__ void gemm8S(
    f32x4 (&acc)[2][2], const u16* __restrict__ wtile, const u16* __restrict__ act,
    const float* __restrict__ src, u16* __restrict__ dst,
    int tid, int w, int lr, int g)
{
  const u16* wl = wtile + (w * 32 + lr) * 32 + g * 8;   // +fp*512, +kt*8192
  bf16x8 a[2][2];
  #pragma unroll
  for (int fp = 0; fp < 2; ++fp) a[0][fp] = *(const bf16x8*)(wl + fp * 512);
  __builtin_amdgcn_sched_barrier(0x38F);   // keep a[0] loads ahead of slot loads
  float4 slot[4];
  if (STG) {
    #pragma unroll
    for (int c = 0; c < 4; ++c)
      slot[c] = ldf4(src + (size_t)(c * 512 + tid) * 4);
  }
  #pragma unroll
  for (int kt = 0; kt < 8; ++kt) {
    const int cur = kt & 1;
    if (kt < 7) {
      #pragma unroll
      for (int fp = 0; fp < 2; ++fp)
        a[cur ^ 1][fp] = *(const bf16x8*)(wl + (kt + 1) * 8192 + fp * 512);
    }
    bf16x8 b[2];
    #pragma unroll
    for (int fq = 0; fq < 2; ++fq) {
      int q = fq * 16 + lr;
      int k = (kt * 32 + g * 8) ^ ((q & 7) << 3);
      b[fq] = *(const bf16x8*)(act + q * HH + k);
    }
    if (STG && (kt & 1)) {
      const int s = kt >> 1;                // 0..3, compile-time after unroll
      int idx = s * 512 + tid;
      int q = idx >> 6, c = (idx & 63) * 4;
      const float4& v = slot[s];
      ushort4 o;
      o.x = (u16)f2bf(v.x); o.y = (u16)f2bf(v.y);
      o.z = (u16)f2bf(v.z); o.w = (u16)f2bf(v.w);
      *(ushort4*)(dst + q * HH + (c ^ ((q & 7) << 3))) = o;
    }
    #pragma unroll
    for (int fp = 0; fp < 2; ++fp)
      #pragma unroll
      for (int fq = 0; fq < 2; ++fq)
        acc[fp][fq] = __builtin_amdgcn_mfma_f32_16x16x32_bf16(a[cur][fp], b[fq], acc[fp][fq], 0, 0, 0);
    __builtin_amdgcn_sched_barrier(0x38F);  // VMEM may not cross iterations
  }
}

// One-shot staging: [32][256] f32 -> swizzled bf16 LDS.
__device__ __forceinline__ void stageDirect(u16* dst, const float* __restrict__ src, int tid) {
  #pragma unroll
  for (int i = 0; i < 4; ++i) {
    int idx = i * 512 + tid;
    float4 v = ldf4(src + (size_t)idx * 4);
    int q = idx >> 6, c = (idx & 63) * 4;
    ushort4 o;
    o.x = (u16)f2bf(v.x); o.y = (u16)f2bf(v.y);
    o.z = (u16)f2bf(v.z); o.w = (u16)f2bf(v.w);
    *(ushort4*)(dst + q * HH + (c ^ ((q & 7) << 3))) = o;
  }
}

// HF (f32, owner-exclusive RMW): HF[q][p] (+)= sn * relu(acc + b1)
template<bool INIT>
__device__ __forceinline__ void hsUpd(
    float* HF, f32x4 (&acc)[2][2], const float* __restrict__ b1,
    float sn, int w, int lr, int g)
{
  #pragma unroll
  for (int fp = 0; fp < 2; ++fp) {
    int p0 = w * 32 + fp * 16 + g * 4;
    float4 bv = *(const float4*)(b1 + p0);
    #pragma unroll
    for (int fq = 0; fq < 2; ++fq) {
      int q = fq * 16 + lr;
      float* addr = HF + q * HH + (p0 ^ ((q & 7) << 3));
      float4 nv;
      nv.x = sn * fmaxf(acc[fp][fq][0] + bv.x, 0.f);
      nv.y = sn * fmaxf(acc[fp][fq][1] + bv.y, 0.f);
      nv.z = sn * fmaxf(acc[fp][fq][2] + bv.z, 0.f);
      nv.w = sn * fmaxf(acc[fp][fq][3] + bv.w, 0.f);
      if (!INIT) {
        float4 old = *(float4*)addr;
        nv.x += old.x; nv.y += old.y; nv.z += old.z; nv.w += old.w;
      }
      *(float4*)addr = nv;
    }
  }
}

// convert HF (f32 [32][256], swizzled) -> bf16 tile (same swizzle)
__device__ __forceinline__ void convertHS(const float* __restrict__ HF, u16* dst, int tid) {
  #pragma unroll
  for (int j = 0; j < 4; ++j) {
    int idx = j * 512 + tid;
    int q = idx >> 6, c = (idx & 63) * 4;
    int sw = c ^ ((q & 7) << 3);
    float4 v = *(const float4*)(HF + q * HH + sw);
    ushort4 o;
    o.x = (u16)f2bf(v.x); o.y = (u16)f2bf(v.y);
    o.z = (u16)f2bf(v.z); o.w = (u16)f2bf(v.w);
    *(ushort4*)(dst + q * HH + sw) = o;
  }
}

// acc -> swizzled bf16 LDS: v = [relu?](acc + bscale*bias)
__device__ __forceinline__ void epiLds(
    u16* buf, f32x4 (&acc)[2][2], const float* __restrict__ bias,
    float bscale, bool doRelu, int w, int lr, int g)
{
  #pragma unroll
  for (int fp = 0; fp < 2; ++fp) {
    int p0 = w * 32 + fp * 16 + g * 4;
    float4 bv = *(const float4*)(bias + p0);
    #pragma unroll
    for (int fq = 0; fq < 2; ++fq) {
      int q = fq * 16 + lr;
      float v0 = acc[fp][fq][0] + bscale * bv.x;
      float v1 = acc[fp][fq][1] + bscale * bv.y;
      float v2 = acc[fp][fq][2] + bscale * bv.z;
      float v3 = acc[fp][fq][3] + bscale * bv.w;
      if (doRelu) {
        v0 = fmaxf(v0, 0.f); v1 = fmaxf(v1, 0.f);
        v2 = fmaxf(v2, 0.f); v3 = fmaxf(v3, 0.f);
      }
      ushort4 o;
      o.x = (u16)f2bf(v0); o.y = (u16)f2bf(v1);
      o.z = (u16)f2bf(v2); o.w = (u16)f2bf(v3);
      *(ushort4*)(buf + q * HH + (p0 ^ ((q & 7) << 3))) = o;
    }
  }
}

// out = recv + gate*(acc + bias)
__device__ __forceinline__ void epiOut(
    f32x4 (&acc)[2][2], const float* __restrict__ bias,
    const float* __restrict__ recv, float* __restrict__ outp,
    float gate, int w, int lr, int g)
{
  #pragma unroll
  for (int fp = 0; fp < 2; ++fp) {
    int p0 = w * 32 + fp * 16 + g * 4;
    float4 bv = *(const float4*)(bias + p0);
    #pragma unroll
    for (int fq = 0; fq < 2; ++fq) {
      int q = fq * 16 + lr;
      float4 rv = *(const float4*)(recv + (size_t)q * HH + p0);
      float4 ov;
      ov.x = rv.x + gate * (acc[fp][fq][0] + bv.x);
      ov.y = rv.y + gate * (acc[fp][fq][1] + bv.y);
      ov.z = rv.z + gate * (acc[fp][fq][2] + bv.z);
      ov.w = rv.w + gate * (acc[fp][fq][3] + bv.w);
      *(float4*)(outp + (size_t)q * HH + p0) = ov;
    }
  }
}

__global__ __launch_bounds__(512, 4) void CacheFuser_73873437491748_kernel(
    const float* __restrict__ recv_k, const float* __restrict__ recv_v,
    const float* __restrict__ shar_k, const float* __restrict__ shar_v,
    const float* __restrict__ ew, const float* __restrict__ alpha,
    const float* __restrict__ ak_b1, const float* __restrict__ ak_b2,
    const float* __restrict__ av_b1, const float* __restrict__ av_b2,
    const float* __restrict__ fk_b1, const float* __restrict__ fk_b2,
    const float* __restrict__ fv_b1, const float* __restrict__ fv_b2,
    const u16* __restrict__ wt, float* __restrict__ out)
{
  __shared__ u16 XA[BM * HH];    // 16 KB input ping (swizzled bf16)
  __shared__ u16 XB[BM * HH];    // 16 KB input pong
  __shared__ float HF[BM * HH];  // 32 KB f32 hidden-sum; later 2x bf16 scratch
  // total 64 KB -> 2 blocks/CU

  const int bid = blockIdx.x;
  const int l = bid & 7, t = bid >> 3;          // layer <-> XCD affinity
  const int tid = threadIdx.x;
  const int w = tid >> 6, lane = tid & 63, lr = lane & 15, g = lane >> 4;

  u16* F0 = (u16*)HF;            // bf16 scratch 0 (agg tile)
  u16* F1 = (u16*)HF + BM * HH;  // bf16 scratch 1 (fuse-hidden tile)

  const size_t row0 = (size_t)t * BM;
  const u16* lw = wt + (size_t)l * LSTRIDE;
  const float gate = 1.f / (1.f + __expf(-2.f * alpha[l]));
  const float* ewl = ew + l * NN;

  stageDirect(XA, shar_k + ((size_t)l * NN * RPL + row0) * HH, tid);  // K sharer0

  #pragma unroll 1
  for (int path = 0; path < 2; ++path) {
    const float* recvB = (path ? recv_v : recv_k) + ((size_t)l * RPL + row0) * HH;
    const float* sharB = (path ? shar_v : shar_k) + ((size_t)l * NN * RPL + row0) * HH;
    const u16* W1  = lw + (path ? O_AVW1 : O_AKW1);
    const u16* W2  = lw + (path ? O_AVW2 : O_AKW2);
    const u16* FW1 = lw + (path ? O_FVW1 : O_FKW1);
    const u16* FW2 = lw + (path ? O_FVW2 : O_FKW2);
    const float* b1  = (path ? av_b1 : ak_b1) + l * HH;
    const float* b2  = (path ? av_b2 : ak_b2) + l * HH;
    const float* fb1 = (path ? fv_b1 : fk_b1) + l * HH;
    const float* fb2 = (path ? fv_b2 : fk_b2) + l * HH;
    float* outp = out + ((size_t)(path * LL + l) * RPL + row0) * HH;

    int cur = path;
    float sS = 0.f;

    #pragma unroll 1
    for (int n = 0; n < NN; ++n) {
      float sn = ewl[n] * 0.25f; sS += sn;
      __syncthreads();                         // input n ready in cur buffer
      u16* XC = cur ? XB : XA;
      u16* XO = cur ? XA : XB;
      const float* nsrc = (n < 3) ? sharB + (size_t)(n + 1) * RPL * HH : recvB;
      f32x4 h[2][2]; zero22(h);
      gemm8S<true>(h, W1, XC, nsrc, XO, tid, w, lr, g);
      if (n == 0) hsUpd<true >(HF, h, b1, sn, w, lr, g);
      else        hsUpd<false>(HF, h, b1, sn, w, lr, g);
      cur ^= 1;
    }
    // after loop: recv in cur buffer, cur^1 dead (last sharer)
    u16* XR = cur ? XB : XA;
    u16* XD = cur ? XA : XB;
    __syncthreads();                           // HF complete; recv staged
    convertHS(HF, XD, tid);                    // XD = bf16(hsum)
    __syncthreads();
    f32x4 agg[2][2]; zero22(agg);
    gemm8S<false>(agg, W2, XD, nullptr, nullptr, tid, w, lr, g);
    epiLds(F0, agg, b2, sS, false, w, lr, g);  // F0 = agg + sS*b2 (HF now dead)
    __syncthreads();                           // F0 ready; XD reads done
    f32x4 h2[2][2]; zero22(h2);
    if (path == 0) {
      // fuse GEMM1 (recv half) while streaming V-path sharer0 -> XD
      gemm8S<true>(h2, FW1, XR, shar_v + ((size_t)l * NN * RPL + row0) * HH, XD,
                   tid, w, lr, g);
    } else {
      gemm8S<false>(h2, FW1, XR, nullptr, nullptr, tid, w, lr, g);
    }
    gemm8S<false>(h2, FW1 + 8 * 8192, F0, nullptr, nullptr, tid, w, lr, g);  // agg half
    epiLds(F1, h2, fb1, 1.f, true, w, lr, g);  // F1 = fuse hidden (disjoint from F0)
    __syncthreads();                           // F1 ready
    f32x4 dd[2][2]; zero22(dd);
    gemm8S<false>(dd, FW2, F1, nullptr, nullptr, tid, w, lr, g);
    epiOut(dd, fb2, recvB, outp, gate, w, lr, g);
    // path1 input (V sharer0) sits in XD; after cur^=1 the loop reads it.
    cur ^= 1;
  }
}

extern "C" void kernel_launch(void* const* d_in, const int* in_sizes, int n_in,
                              void* d_out, int out_size, void* d_ws, size_t ws_size,
                              hipStream_t stream)
{
  const float* recv_k = (const float*)d_in[0];
  const float* recv_v = (const float*)d_in[1];
  const float* shar_k = (const float*)d_in[2];
  const float* shar_v = (const float*)d_in[3];
  const float* ew     = (const float*)d_in[4];
  const float* alpha  = (const float*)d_in[5];
  const float* ak_w1 = (const float*)d_in[6];  const float* ak_b1 = (const float*)d_in[7];
  const float* ak_w2 = (const float*)d_in[8];  const float* ak_b2 = (const float*)d_in[9];
  const float* av_w1 = (const float*)d_in[10]; const float* av_b1 = (const float*)d_in[11];
  const float* av_w2 = (const float*)d_in[12]; const float* av_b2 = (const float*)d_in[13];
  const float* fk_w1 = (const float*)d_in[14]; const float* fk_b1 = (const float*)d_in[15];
  const float* fk_w2 = (const float*)d_in[16]; const float* fk_b2 = (const float*)d_in[17];
  const float* fv_w1 = (const float*)d_in[18]; const float* fv_b1 = (const float*)d_in[19];
  const float* fv_w2 = (const float*)d_in[20]; const float* fv_b2 = (const float*)d_in[21];
  u16* wtw = (u16*)d_ws;          // 10485760 B
  float* outp = (float*)d_out;

  prep_wt_k<<<dim3(128, 8, 8), dim3(256), 0, stream>>>(
      ak_w1, ak_w2, av_w1, av_w2, fk_w1, fk_w2, fv_w1, fv_w2, wtw);

  CacheFuser_73873437491748_kernel<<<dim3(2048), dim3(512), 0, stream>>>(
      recv_k, recv_v, shar_k, shar_v, ew, alpha,
      ak_b1, ak_b2, av_b1, av_b2, fk_b1, fk_b2, fv_b1, fv_b2, wtw, outp);
}